// Round 3
// baseline (478.542 us; speedup 1.0000x reference)
//
#include <hip/hip_runtime.h>
#include <hip/hip_fp16.h>

// GaussianBlur, fused single-kernel banded-Toeplitz GEMM on matrix cores.
// R5: block = (bc, 32 out rows, full width). Per 64-col strip: stage input
// (16ns x 64) transposed f16 in LDS, operand-swapped vertical MFMA
// (D = I^T * W^T -> lane=y, regs=consecutive x -> half2 vtmp writes), vtmp
// [32][704] in LDS only (no HBM tmp). Reflect x-halo filled LDS->LDS, then
// horizontal MFMA identical to the verified round-2 pass2. All fragment
// byte-patterns reuse verified round-2 mappings. XCD-chunked bc mapping.
// ws: unused.

#define B_   64
#define C_   3
#define H_   512
#define W_   512
#define RMAX 80
#define NW   224     // w2 pair-table entries, d in [-112, 111]
#define WOFF 112
#define SB_R 192     // sbuf i' capacity (= 16 * ns_max)
#define IW   704     // vtmp stride in halfs (88 chunks; key&7 XOR closed)

typedef float    f32x16 __attribute__((ext_vector_type(16)));
typedef _Float16 f16x8  __attribute__((ext_vector_type(8)));

__device__ __forceinline__ int refl(int g) {
    int a = g < 0 ? -g : g;        // reflect (no edge repeat)
    int c = 1022 - a;              // 2*(H-1) - a
    return a < c ? a : c;
}

// w2v[t] = halves( W(t-112), W(t-111) ); returns radius r. scr/red overlay
// the staging LDS (fully consumed before staging begins).
__device__ __forceinline__ int make_weights(float sigma, float* scr, float* red,
                                            unsigned int* w2v, int tid) {
    const int d = tid - 128;                 // [-128,127] covers [-80,80]
    float e = 0.f;
    if (d >= -RMAX && d <= RMAX) {
        const float u = (float)d / sigma;
        e = expf(-0.5f * u * u);
    }
    scr[tid] = e;
    red[tid] = e;
    __syncthreads();
    for (int s = 128; s > 0; s >>= 1) {
        if (tid < s) red[tid] += red[tid + s];
        __syncthreads();
    }
    const float inv = 1.0f / red[0];
    int r = (int)ceilf(6.0f * sigma);        // tail beyond 6 sigma < 7e-10
    if (r > RMAX) r = RMAX;
    if (r < 1)    r = 1;
    if (tid < NW) {
        const int d0 = tid - 112;
        const float w0 = (d0     >= -r && d0     <= r) ? scr[tid + 16] * inv : 0.f;
        const float w1 = (d0 + 1 >= -r && d0 + 1 <= r) ? scr[tid + 17] * inv : 0.f;
        w2v[tid] = (unsigned int)__half_as_ushort(__float2half(w0)) |
                   ((unsigned int)__half_as_ushort(__float2half(w1)) << 16);
    }
    __syncthreads();                         // scr dead -> staging may reuse
    return r;
}

__global__ __launch_bounds__(256, 2) void k_fused(const float* __restrict__ x,
                                                  const float* __restrict__ sig,
                                                  const int* __restrict__ steps,
                                                  float* __restrict__ out) {
    __shared__ __align__(16) unsigned short sbuf[64 * SB_R];  // 24576 B
    __shared__ __align__(16) unsigned short vtmp[32 * IW];    // 45056 B
    __shared__ unsigned int w2v[NW];                          // 896 B
    const int tid = threadIdx.x;
    const int id  = blockIdx.x;
    // XCD-chunked: each of 8 XCD groups owns 24 consecutive bc (full images)
    const int xcd = id & 7, idx = id >> 3;
    const int bc  = xcd * 24 + (idx >> 4);
    const int y0  = (idx & 15) << 5;         // 16 chunks of 32 out rows
    const int b   = bc / C_;
    const size_t img = (size_t)bc * (H_ * (size_t)W_);

    const float sigma = sig[steps[b]] + 1e-6f;
    float* scr = (float*)sbuf;
    const int r  = make_weights(sigma, scr, scr + 256, w2v, tid);
    const int rp = (r + 7) & ~7;
    const int ns = (r + rp + 47) >> 4;       // K-steps (16*ns >= r+rp+32)
    const int Rr = 16 * ns;                  // staged i' rows (<= 192)
    const int ystart = y0 - rp;

    const int l  = tid & 63;
    const int wv = tid >> 6;
    const int m  = l & 31;
    const int g  = l >> 5;
    const int ebase = WOFF + 8 * g - rp - m; // Toeplitz w2 entry, k-slice g

    const int p0 = tid & 15;                 // staging: row-pair id
    const int x4 = tid >> 4;                 // staging: 4-col group

    for (int s = 0; s < 8; ++s) {
        {   // stage strip s: rows [ystart, ystart+Rr) x cols [64s, 64s+64),
            // transposed sbuf[x][i'], chunk-XOR key (x&3) (verified pattern)
            const float* gsrc = x + img + (64 * s + x4 * 4);
            const int i7 = (2 * p0) & 7;
            for (int pr = p0; 2 * pr < Rr; pr += 16) {
                const int i0  = 2 * pr;
                const int gy0 = refl(ystart + i0);
                const int gy1 = refl(ystart + i0 + 1);
                const float4 va = *(const float4*)(gsrc + (size_t)gy0 * W_);
                const float4 vb = *(const float4*)(gsrc + (size_t)gy1 * W_);
                const float* fa = (const float*)&va;
                const float* fb = (const float*)&vb;
                const int c = i0 >> 3;
                #pragma unroll
                for (int q = 0; q < 4; ++q) {
                    const int xq = x4 * 4 + q;
                    *(__half2*)(sbuf + xq * SB_R + ((c ^ (xq & 3)) << 3) + i7) =
                        __floats2half2_rn(fa[q], fb[q]);
                }
            }
        }
        __syncthreads();
        if (wv < 2) {                        // vertical MFMA: 2 x-tiles
            const unsigned short* arow = sbuf + (32 * wv + m) * SB_R;
            const int akey = m & 3;
            f32x16 acc = {};
            for (int sk = 0; sk < ns; ++sk) {
                const int e = ebase + 16 * sk;
                union { unsigned int u[4]; f16x8 h; } Wf;
                Wf.u[0] = w2v[e];     Wf.u[1] = w2v[e + 2];
                Wf.u[2] = w2v[e + 4]; Wf.u[3] = w2v[e + 6];
                const f16x8 af = *(const f16x8*)(arow + (((2 * sk + g) ^ akey) << 3));
                acc = __builtin_amdgcn_mfma_f32_32x32x16_f16(af, Wf.h, acc, 0, 0, 0);
            }
            // D[x][y]: lane holds y = m, x = 64s + 32wv + 8(t>>1) + 4g + 2(t&1) + {0,1}
            const int ybase = m * IW;
            const int key   = m & 7;
            #pragma unroll
            for (int t = 0; t < 8; ++t) {
                const int off4 = 4 * g + 2 * (t & 1);
                const int c2   = (rp >> 3) + 8 * s + 4 * wv + (t >> 1);
                *(__half2*)(vtmp + ybase + ((c2 ^ key) << 3) + off4) =
                    __floats2half2_rn(acc[2 * t], acc[2 * t + 1]);
            }
        }
        __syncthreads();
    }

    {   // reflect x-halo LDS->LDS: i' = global_x + rp, interior [rp, rp+512)
        const int nh   = 16 * ns - 32;       // halo halfs per row
        const int row  = tid >> 3, cq = tid & 7;
        const int rbase = row * IW, key = row & 7;
        for (int e = cq; e < nh; e += 8) {
            const int ip = e < rp ? e : e + 512;
            const int is = refl(ip - rp) + rp;   // source always interior
            const unsigned short v =
                vtmp[rbase + (((is >> 3) ^ key) << 3) + (is & 7)];
            vtmp[rbase + (((ip >> 3) ^ key) << 3) + (ip & 7)] = v;
        }
    }
    __syncthreads();

    // horizontal MFMA (round-2 pass2 structure): wave wv -> n-tiles 4wv..4wv+3
    const unsigned short* shm = vtmp + m * IW;
    const int akey = m & 7;
    const int c0   = 16 * wv + g;
    f32x16 a0 = {}, a1 = {}, a2 = {}, a3 = {};
    for (int sk = 0; sk < ns; ++sk) {
        const int e = ebase + 16 * sk;
        union { unsigned int u[4]; f16x8 h; } Wf;
        Wf.u[0] = w2v[e];     Wf.u[1] = w2v[e + 2];
        Wf.u[2] = w2v[e + 4]; Wf.u[3] = w2v[e + 6];
        const int cs = c0 + 2 * sk;
        const f16x8 f0 = *(const f16x8*)(shm + (((cs     ) ^ akey) << 3));
        const f16x8 f1 = *(const f16x8*)(shm + (((cs +  4) ^ akey) << 3));
        const f16x8 f2 = *(const f16x8*)(shm + (((cs +  8) ^ akey) << 3));
        const f16x8 f3 = *(const f16x8*)(shm + (((cs + 12) ^ akey) << 3));
        a0 = __builtin_amdgcn_mfma_f32_32x32x16_f16(f0, Wf.h, a0, 0, 0, 0);
        a1 = __builtin_amdgcn_mfma_f32_32x32x16_f16(f1, Wf.h, a1, 0, 0, 0);
        a2 = __builtin_amdgcn_mfma_f32_32x32x16_f16(f2, Wf.h, a2, 0, 0, 0);
        a3 = __builtin_amdgcn_mfma_f32_32x32x16_f16(f3, Wf.h, a3, 0, 0, 0);
    }

    float* ob = out + img + (size_t)y0 * W_ + 128 * wv + m;
    #pragma unroll
    for (int reg = 0; reg < 16; ++reg) {
        const int orow = (reg & 3) + 8 * (reg >> 2) + 4 * g;
        float* orp_ = ob + (size_t)orow * W_;
        orp_[0]  = a0[reg];
        orp_[32] = a1[reg];
        orp_[64] = a2[reg];
        orp_[96] = a3[reg];
    }
}

extern "C" void kernel_launch(void* const* d_in, const int* in_sizes, int n_in,
                              void* d_out, int out_size, void* d_ws, size_t ws_size,
                              hipStream_t stream) {
    const float* x     = (const float*)d_in[0];
    const float* sig   = (const float*)d_in[1];
    const int*   steps = (const int*)d_in[2];
    float* out = (float*)d_out;
    (void)d_ws; (void)ws_size;

    k_fused<<<B_ * C_ * 16, 256, 0, stream>>>(x, sig, steps, out);
}

// Round 4
// 363.787 us; speedup vs baseline: 1.3154x; 1.3154x over previous
//
#include <hip/hip_runtime.h>
#include <hip/hip_fp16.h>

// GaussianBlur fused banded-Toeplitz GEMM, round 4.
// R6: vertical pass reads the image DIRECTLY from global (L2/L3-resident,
// coalesced across lanes) into MFMA A-fragments -- no LDS staging, no
// per-strip barriers. All 4 waves compute 4 x-tiles each (sk-outer loop:
// one weight frag + one reflect computation shared across 4 tiles, 32
// loads in flight). vtmp [32][704] f16 stays LDS-only; key(row) =
// (row&7)^(row>>3) kills the 4-way row-alias bank conflicts on both the
// vertical half2 writes and the horizontal ds_read_b128. 3 barriers total,
// LDS 46 KB -> 3 blocks/CU. Horizontal phase = verified round-2 pattern.
// ws: unused.

#define B_   64
#define C_   3
#define H_   512
#define W_   512
#define RMAX 80
#define NW   224     // w2 pair-table entries, d in [-112, 111]
#define WOFF 112
#define IW   704     // vtmp stride in halfs (88 chunks; XOR key 0..7 closed)

typedef float    f32x16 __attribute__((ext_vector_type(16)));
typedef _Float16 f16x8  __attribute__((ext_vector_type(8)));

#define KEYR(row) (((row) & 7) ^ ((row) >> 3))   // row in [0,32)

__device__ __forceinline__ int refl(int g) {
    int a = g < 0 ? -g : g;        // reflect (no edge repeat)
    int c = 1022 - a;              // 2*(H-1) - a
    return a < c ? a : c;
}

// w2v[t] = halves( W(t-112), W(t-111) ); returns radius r. scr/red overlay
// vtmp (fully consumed before any vtmp write).
__device__ __forceinline__ int make_weights(float sigma, float* scr, float* red,
                                            unsigned int* w2v, int tid) {
    const int d = tid - 128;                 // [-128,127] covers [-80,80]
    float e = 0.f;
    if (d >= -RMAX && d <= RMAX) {
        const float u = (float)d / sigma;
        e = expf(-0.5f * u * u);
    }
    scr[tid] = e;
    red[tid] = e;
    __syncthreads();
    for (int s = 128; s > 0; s >>= 1) {
        if (tid < s) red[tid] += red[tid + s];
        __syncthreads();
    }
    const float inv = 1.0f / red[0];
    int r = (int)ceilf(6.0f * sigma);        // tail beyond 6 sigma < 7e-10
    if (r > RMAX) r = RMAX;
    if (r < 1)    r = 1;
    if (tid < NW) {
        const int d0 = tid - 112;
        const float w0 = (d0     >= -r && d0     <= r) ? scr[tid + 16] * inv : 0.f;
        const float w1 = (d0 + 1 >= -r && d0 + 1 <= r) ? scr[tid + 17] * inv : 0.f;
        w2v[tid] = (unsigned int)__half_as_ushort(__float2half(w0)) |
                   ((unsigned int)__half_as_ushort(__float2half(w1)) << 16);
    }
    __syncthreads();                         // scr dead after this
    return r;
}

__global__ __launch_bounds__(256, 3) void k_fused(const float* __restrict__ x,
                                                  const float* __restrict__ sig,
                                                  const int* __restrict__ steps,
                                                  float* __restrict__ out) {
    __shared__ __align__(16) unsigned short vtmp[32 * IW];    // 45056 B
    __shared__ unsigned int w2v[NW];                          // 896 B
    const int tid = threadIdx.x;
    const int id  = blockIdx.x;
    // HW round-robins id%8 across XCDs -> all 16 y-blocks of one bc (1 MB
    // image) land on one XCD's L2.
    const int xcd = id & 7, idx = id >> 3;
    const int bc  = xcd * 24 + (idx >> 4);
    const int y0  = (idx & 15) << 5;         // 16 chunks of 32 out rows
    const int b   = bc / C_;
    const size_t img = (size_t)bc * (H_ * (size_t)W_);

    const float sigma = sig[steps[b]] + 1e-6f;
    float* scr = (float*)vtmp;
    const int r  = make_weights(sigma, scr, scr + 256, w2v, tid);
    const int rp = (r + 7) & ~7;
    const int ns = (r + rp + 47) >> 4;       // K-steps (16*ns >= r+rp+32)
    const int ystart = y0 - rp;

    const int l  = tid & 63;
    const int wv = tid >> 6;
    const int m  = l & 31;
    const int g  = l >> 5;
    const int ebase = WOFF + 8 * g - rp - m; // Toeplitz w2 entry, k-slice g

    // ---- vertical: wave wv -> x-tiles 128*wv + {0,32,64,96}, no LDS in ----
    const bool interior = (ystart >= 0) && (ystart + 16 * ns <= H_);
    const float* gcol = x + img + 128 * wv + m;  // lane's column, tile 0
    f32x16 a0 = {}, a1 = {}, a2 = {}, a3 = {};
    for (int sk = 0; sk < ns; ++sk) {
        const int k0 = 16 * sk + 8 * g;
        float v0[8], v1[8], v2[8], v3[8];
        if (interior) {
            const float* p = gcol + (size_t)(ystart + k0) * W_;
            #pragma unroll
            for (int j = 0; j < 8; ++j) {
                v0[j] = p[(size_t)j * W_];
                v1[j] = p[(size_t)j * W_ + 32];
                v2[j] = p[(size_t)j * W_ + 64];
                v3[j] = p[(size_t)j * W_ + 96];
            }
        } else {
            #pragma unroll
            for (int j = 0; j < 8; ++j) {
                const float* p = gcol + (size_t)refl(ystart + k0 + j) * W_;
                v0[j] = p[0]; v1[j] = p[32]; v2[j] = p[64]; v3[j] = p[96];
            }
        }
        union { unsigned int u[4]; f16x8 h; } A0, A1, A2, A3, Wf;
        #pragma unroll
        for (int q = 0; q < 4; ++q) {
            __half2 h0 = __floats2half2_rn(v0[2*q], v0[2*q+1]);
            __half2 h1 = __floats2half2_rn(v1[2*q], v1[2*q+1]);
            __half2 h2 = __floats2half2_rn(v2[2*q], v2[2*q+1]);
            __half2 h3 = __floats2half2_rn(v3[2*q], v3[2*q+1]);
            A0.u[q] = *(unsigned int*)&h0;
            A1.u[q] = *(unsigned int*)&h1;
            A2.u[q] = *(unsigned int*)&h2;
            A3.u[q] = *(unsigned int*)&h3;
        }
        const int e = ebase + 16 * sk;
        Wf.u[0] = w2v[e];     Wf.u[1] = w2v[e + 2];
        Wf.u[2] = w2v[e + 4]; Wf.u[3] = w2v[e + 6];
        a0 = __builtin_amdgcn_mfma_f32_32x32x16_f16(A0.h, Wf.h, a0, 0, 0, 0);
        a1 = __builtin_amdgcn_mfma_f32_32x32x16_f16(A1.h, Wf.h, a1, 0, 0, 0);
        a2 = __builtin_amdgcn_mfma_f32_32x32x16_f16(A2.h, Wf.h, a2, 0, 0, 0);
        a3 = __builtin_amdgcn_mfma_f32_32x32x16_f16(A3.h, Wf.h, a3, 0, 0, 0);
    }
    {   // D: lane holds y = m; regs = x pairs -> half2 vtmp writes
        const int ybase = m * IW;
        const int key   = KEYR(m);
        const int cb    = (rp >> 3) + 16 * wv;   // chunk of tile-0 x base
        #pragma unroll
        for (int t = 0; t < 8; ++t) {
            const int off4 = 4 * g + 2 * (t & 1);
            const int c2   = cb + (t >> 1);
            *(__half2*)(vtmp + ybase + (((c2     ) ^ key) << 3) + off4) =
                __floats2half2_rn(a0[2*t], a0[2*t+1]);
            *(__half2*)(vtmp + ybase + (((c2 +  4) ^ key) << 3) + off4) =
                __floats2half2_rn(a1[2*t], a1[2*t+1]);
            *(__half2*)(vtmp + ybase + (((c2 +  8) ^ key) << 3) + off4) =
                __floats2half2_rn(a2[2*t], a2[2*t+1]);
            *(__half2*)(vtmp + ybase + (((c2 + 12) ^ key) << 3) + off4) =
                __floats2half2_rn(a3[2*t], a3[2*t+1]);
        }
    }
    __syncthreads();

    {   // reflect x-halo LDS->LDS: i' = global_x + rp, interior [rp, rp+512)
        const int nh   = 16 * ns - 32;       // halo halfs per row
        const int row  = tid >> 3, cq = tid & 7;
        const int rbase = row * IW, key = KEYR(row);
        for (int e = cq; e < nh; e += 8) {
            const int ip = e < rp ? e : e + 512;
            const int is = refl(ip - rp) + rp;   // source always interior
            const unsigned short v =
                vtmp[rbase + (((is >> 3) ^ key) << 3) + (is & 7)];
            vtmp[rbase + (((ip >> 3) ^ key) << 3) + (ip & 7)] = v;
        }
    }
    __syncthreads();

    // ---- horizontal (verified round-2 structure): wave wv -> n-tiles 4wv.. ----
    const unsigned short* shm = vtmp + m * IW;
    const int akey = KEYR(m);
    const int c0   = 16 * wv + g;
    f32x16 h0 = {}, h1 = {}, h2 = {}, h3 = {};
    for (int sk = 0; sk < ns; ++sk) {
        const int e = ebase + 16 * sk;
        union { unsigned int u[4]; f16x8 h; } Wf;
        Wf.u[0] = w2v[e];     Wf.u[1] = w2v[e + 2];
        Wf.u[2] = w2v[e + 4]; Wf.u[3] = w2v[e + 6];
        const int cs = c0 + 2 * sk;
        const f16x8 f0 = *(const f16x8*)(shm + (((cs     ) ^ akey) << 3));
        const f16x8 f1 = *(const f16x8*)(shm + (((cs +  4) ^ akey) << 3));
        const f16x8 f2 = *(const f16x8*)(shm + (((cs +  8) ^ akey) << 3));
        const f16x8 f3 = *(const f16x8*)(shm + (((cs + 12) ^ akey) << 3));
        h0 = __builtin_amdgcn_mfma_f32_32x32x16_f16(f0, Wf.h, h0, 0, 0, 0);
        h1 = __builtin_amdgcn_mfma_f32_32x32x16_f16(f1, Wf.h, h1, 0, 0, 0);
        h2 = __builtin_amdgcn_mfma_f32_32x32x16_f16(f2, Wf.h, h2, 0, 0, 0);
        h3 = __builtin_amdgcn_mfma_f32_32x32x16_f16(f3, Wf.h, h3, 0, 0, 0);
    }

    float* ob = out + img + (size_t)y0 * W_ + 128 * wv + m;
    #pragma unroll
    for (int reg = 0; reg < 16; ++reg) {
        const int orow = (reg & 3) + 8 * (reg >> 2) + 4 * g;
        float* orp_ = ob + (size_t)orow * W_;
        orp_[0]  = h0[reg];
        orp_[32] = h1[reg];
        orp_[64] = h2[reg];
        orp_[96] = h3[reg];
    }
}

extern "C" void kernel_launch(void* const* d_in, const int* in_sizes, int n_in,
                              void* d_out, int out_size, void* d_ws, size_t ws_size,
                              hipStream_t stream) {
    const float* x     = (const float*)d_in[0];
    const float* sig   = (const float*)d_in[1];
    const int*   steps = (const int*)d_in[2];
    float* out = (float*)d_out;
    (void)d_ws; (void)ws_size;

    k_fused<<<B_ * C_ * 16, 256, 0, stream>>>(x, sig, steps, out);
}